// Round 15
// baseline (822.276 us; speedup 1.0000x reference)
//
#include <hip/hip_runtime.h>

typedef __attribute__((ext_vector_type(8))) short short8;
typedef __attribute__((ext_vector_type(4))) float f32x4;
typedef __attribute__((ext_vector_type(16))) float f32x16;

#define DEV __device__ __forceinline__

DEV float bf2f(unsigned short u) { return __uint_as_float(((unsigned)u) << 16); }
DEV unsigned short f2bf(float f) {
  unsigned u = __float_as_uint(f);
  u += 0x7FFF + ((u >> 16) & 1);   // RNE
  return (unsigned short)(u >> 16);
}

#define GLOAD_LDS16(gptr, lptr)                                                              \
  __builtin_amdgcn_global_load_lds((const __attribute__((address_space(1))) void*)(gptr),   \
                                   (__attribute__((address_space(3))) void*)(lptr), 16, 0, 0)

// ---------------------------------------------------------------------------
// Weight prep: W (K x N, fp32) -> Wt (N x K, bf16)
// ---------------------------------------------------------------------------
__global__ __launch_bounds__(256) void wt_transpose_bf16(const float* __restrict__ W,
                                                         unsigned short* __restrict__ Wt,
                                                         int K, int N) {
  __shared__ float t[32][33];
  int k0 = blockIdx.x * 32, n0 = blockIdx.y * 32;
  int tx = threadIdx.x, ty = threadIdx.y;  // 32 x 8
#pragma unroll
  for (int i = 0; i < 4; ++i)
    t[ty + 8 * i][tx] = W[(long)(k0 + ty + 8 * i) * N + n0 + tx];
  __syncthreads();
#pragma unroll
  for (int i = 0; i < 4; ++i)
    Wt[(long)(n0 + ty + 8 * i) * K + k0 + tx] = f2bf(t[tx][ty + 8 * i]);
}

// ---------------------------------------------------------------------------
// Row LayerNorm (D=1024 fixed): fp32 in -> bf16 out
// ---------------------------------------------------------------------------
__global__ __launch_bounds__(256) void ln_to_bf16(const float* __restrict__ x,
                                                  const float* __restrict__ g,
                                                  const float* __restrict__ b,
                                                  unsigned short* __restrict__ y) {
  const long row = blockIdx.x;
  const int tid = threadIdx.x;
  float4 v = *(const float4*)(x + row * 1024 + tid * 4);
  float s = v.x + v.y + v.z + v.w;
  float s2 = v.x * v.x + v.y * v.y + v.z * v.z + v.w * v.w;
#pragma unroll
  for (int o = 32; o > 0; o >>= 1) { s += __shfl_down(s, o); s2 += __shfl_down(s2, o); }
  __shared__ float red[8];
  __shared__ float mv[2];
  int wv = tid >> 6, ln = tid & 63;
  if (ln == 0) { red[wv] = s; red[4 + wv] = s2; }
  __syncthreads();
  if (tid == 0) {
    float a = red[0] + red[1] + red[2] + red[3];
    float q = red[4] + red[5] + red[6] + red[7];
    float mean = a * (1.f / 1024.f);
    mv[0] = mean;
    mv[1] = rsqrtf(q * (1.f / 1024.f) - mean * mean + 1e-5f);
  }
  __syncthreads();
  float mean = mv[0], rstd = mv[1];
  float4 gg = *(const float4*)(g + tid * 4);
  float4 bb = *(const float4*)(b + tid * 4);
  ushort4 o;
  o.x = f2bf((v.x - mean) * rstd * gg.x + bb.x);
  o.y = f2bf((v.y - mean) * rstd * gg.y + bb.y);
  o.z = f2bf((v.z - mean) * rstd * gg.z + bb.z);
  o.w = f2bf((v.w - mean) * rstd * gg.w + bb.w);
  *(ushort4*)(y + row * 1024 + tid * 4) = o;
}

// epilogue helper
// EPI: 0 +bias -> bf16 row-major (qf) | 1 +bias -> bf16 v_flat permute
//      2 +bias+res -> fp32 | 3 +bias GELU -> bf16 | 5 +res -> fp32
template <int EPI>
DEV void epi_store(void* out, const float* res, long grow, long gcol, int N, float val) {
  if (EPI == 0) {
    ((unsigned short*)out)[grow * N + gcol] = f2bf(val);
  } else if (EPI == 1) {
    const int b_ = (int)(grow >> 10), hw = (int)(grow & 1023);
    const int nh = (int)(gcol >> 6), hd = (int)(gcol & 63);
    ((unsigned short*)out)[((long)(b_ * 16 + nh) << 16) + hw * 64 + hd] = f2bf(val);
  } else if (EPI == 2) {
    ((float*)out)[grow * N + gcol] = val + res[grow * N + gcol];
  } else if (EPI == 3) {
    float gl = 0.5f * val * (1.f + erff(val * 0.70710678118654752f));
    ((unsigned short*)out)[grow * N + gcol] = f2bf(gl);
  } else {  // EPI == 5
    ((float*)out)[grow * N + gcol] = val + res[grow * N + gcol];
  }
}

// ---------------------------------------------------------------------------
// gemm32 (proven R13/R14 control): 128x128 tile, BK=64, 4 waves, 32x32x16
// MFMA, row-pair swizzle (0 conflicts), 4 blocks/CU, supertiled 1D grid.
// ---------------------------------------------------------------------------
template <int EPI>
__global__ __launch_bounds__(256, 4) void gemm32(const unsigned short* __restrict__ A,
                                                 const unsigned short* __restrict__ Bt,
                                                 const float* __restrict__ bias,
                                                 const float* __restrict__ res,
                                                 void* __restrict__ out,
                                                 int N, int K, int ldb, int n_mt) {
  __shared__ __align__(16) char smem[32768];  // A 16KB + B 16KB
  const int tid = threadIdx.x;
  const int wave = tid >> 6, lane = tid & 63;
  const int wm = wave >> 1, wn = wave & 1;

  const int st = blockIdx.x >> 5, wi = blockIdx.x & 31;
  const int nsm = n_mt >> 3;
  const int stm = st % nsm, stn = st / nsm;
  const long row0 = (long)(stm * 8 + (wi & 7)) * 128;
  const long col0 = (long)(stn * 4 + (wi >> 3)) * 128;

  f32x16 acc[2][2];
#pragma unroll
  for (int i = 0; i < 2; ++i)
#pragma unroll
    for (int n = 0; n < 2; ++n)
#pragma unroll
      for (int r = 0; r < 16; ++r) acc[i][n][r] = 0.f;

  const int rin = lane >> 3, ch = lane & 7;  // chunk = 1KB = 8 rows x 128B

  for (int kt = 0; kt < K; kt += 64) {
#pragma unroll
    for (int i = 0; i < 4; ++i) {
      const int c = wave * 4 + i;
      const int r = c * 8 + rin;
      const int kg = ch ^ ((r >> 1) & 7);
      GLOAD_LDS16(A + (row0 + r) * (long)K + kt + kg * 8, smem + c * 1024);
      GLOAD_LDS16(Bt + (col0 + r) * (long)ldb + kt + kg * 8, smem + 16384 + c * 1024);
    }
    asm volatile("s_waitcnt vmcnt(0)" ::: "memory");
    __syncthreads();
#pragma unroll
    for (int ks = 0; ks < 4; ++ks) {
      short8 af[2], bfr[2];
      const int kc = ks * 2 + (lane >> 5);
#pragma unroll
      for (int mi = 0; mi < 2; ++mi) {
        const int rowa = wm * 64 + mi * 32 + (lane & 31);
        af[mi] = *(const short8*)(smem + rowa * 128 + (kc ^ ((rowa >> 1) & 7)) * 16);
      }
#pragma unroll
      for (int ni = 0; ni < 2; ++ni) {
        const int rowb = wn * 64 + ni * 32 + (lane & 31);
        bfr[ni] = *(const short8*)(smem + 16384 + rowb * 128 + (kc ^ ((rowb >> 1) & 7)) * 16);
      }
#pragma unroll
      for (int mi = 0; mi < 2; ++mi)
#pragma unroll
        for (int ni = 0; ni < 2; ++ni)
          acc[mi][ni] =
              __builtin_amdgcn_mfma_f32_32x32x16_bf16(af[mi], bfr[ni], acc[mi][ni], 0, 0, 0);
    }
    __syncthreads();
  }

  const int lc = lane & 31, lh = lane >> 5;
#pragma unroll
  for (int mi = 0; mi < 2; ++mi)
#pragma unroll
    for (int ni = 0; ni < 2; ++ni) {
      const long gcol = col0 + wn * 64 + ni * 32 + lc;
      const float bvv = (EPI == 5) ? 0.f : bias[gcol];
#pragma unroll
      for (int reg = 0; reg < 16; ++reg) {
        const long grow = row0 + wm * 64 + mi * 32 + (reg & 3) + 8 * (reg >> 2) + 4 * lh;
        epi_store<EPI>(out, res, grow, gcol, N, acc[mi][ni][reg] + bvv);
      }
    }
}

// ---------------------------------------------------------------------------
// gemm8p (TEST ARM): 256x256 tile, BK=64, 512 thr = 8 waves (2M x 4N),
// per-wave 128x64 via 16x16x32 MFMA (acc 8x4 f32x4 = 128 VGPR).
// 8 half-tile LDS slots x 16KB = 128KB. Stage order per K-tile:
// h = 4T + {0:B0, 1:B1, 2:A0, 3:A1}; slot = h&7; stage-ahead = 6 phases
// (phase P stages h = P+6). 4 phases per K-tile, each: {ds_read subtile,
// stage 1 half-tile, [vmcnt(4) at p3], barrier, lgkmcnt(0)+sched_barrier,
// setprio(1), 16 MFMA, setprio(0), barrier}. vmcnt(4) once per K-tile
// guarantees next tile fully landed (2 half-tiles in flight max).
// Slot-overwrite safety: every slot is re-staged >=1 barrier after its
// last read (B last read p1, restaged p2/p3; A last read p2, restaged
// p0/p1 of next tile). Row-pair swizzle as gemm32 (0 conflicts).
// ---------------------------------------------------------------------------
template <int EPI>
__global__ __launch_bounds__(512, 2) void gemm8p(const unsigned short* __restrict__ A,
                                                 const unsigned short* __restrict__ Bt,
                                                 const float* __restrict__ bias,
                                                 const float* __restrict__ res,
                                                 void* __restrict__ out,
                                                 int N, int K, int ldb, int n_mt) {
  __shared__ __align__(16) char smem[131072];  // 8 x 16KB half-tile ring
  const int tid = threadIdx.x;
  const int wave = tid >> 6, lane = tid & 63;
  const int wm = wave >> 2, wn = wave & 3;  // 2M x 4N
  const int st = blockIdx.x >> 5, wi = blockIdx.x & 31;
  const int nsm = n_mt >> 3;
  const long row0 = (long)((st % nsm) * 8 + (wi & 7)) * 256;
  const long col0 = (long)((st / nsm) * 4 + (wi >> 3)) * 256;
  const int NT = K >> 6;
  const int NP = NT << 2;  // total half-tiles

  f32x4 acc[8][4];
#pragma unroll
  for (int i = 0; i < 8; ++i)
#pragma unroll
    for (int n = 0; n < 4; ++n) acc[i][n] = f32x4{0.f, 0.f, 0.f, 0.f};

  // stage half-tile h: q = h&3 (0:B0 1:B1 2:A0 3:A1), kt = (h>>2)*64
  auto STAGE = [&](int h) {
    const int q = h & 3, slot = h & 7, kt = (h >> 2) << 6;
    const unsigned short* base = (q < 2) ? Bt : A;
    const long ld = (q < 2) ? (long)ldb : (long)K;
    const long r0 = ((q < 2) ? col0 : row0) + (long)(q & 1) * 128;
    char* dst = smem + slot * 16384 + wave * 1024;
#pragma unroll
    for (int j = 0; j < 2; ++j) {
      const int row = j * 64 + wave * 8 + (lane >> 3);
      const int kg = (lane & 7) ^ ((row >> 1) & 7);  // inverse swizzle on source
      GLOAD_LDS16(base + (r0 + row) * ld + kt + kg * 8, dst + j * 8192);
    }
  };
  // swizzled fragment read from half-slot: rowh in [0,128), ks in {0,1}
  auto RD = [&](int slot, int rowh, int ks) -> short8 {
    const int pos = ((ks << 2) + (lane >> 4)) ^ ((rowh >> 1) & 7);
    return *(const short8*)(smem + slot * 16384 + rowh * 128 + pos * 16);
  };

  // prologue: tile0 B0,B1,A0,A1 + tile1 B0,B1 (stage-ahead 6)
#pragma unroll
  for (int h = 0; h < 6; ++h)
    if (h < NP) STAGE(h);
  asm volatile("s_waitcnt vmcnt(4)" ::: "memory");  // tile0 (8 loads) landed
  __builtin_amdgcn_s_barrier();

  short8 af[4][2], bf[2][2][2];  // bf[nh][nf][ks]
  const int la15 = lane & 15;

  for (int T = 0; T < NT; ++T) {
    const int P0 = T << 2;
    const int slA0 = ((P0 + 2)) & 7, slA1 = (P0 + 3) & 7;
    const int slB = (P0 + (wn >> 1)) & 7;  // this wave's B-half slot base (B0/B1 by wn)
    const int browb = (wn & 1) * 64;

    // ===== phase 0: quadrant (mh0, nh0) =====
#pragma unroll
    for (int mf = 0; mf < 4; ++mf)
#pragma unroll
      for (int ks = 0; ks < 2; ++ks)
        af[mf][ks] = RD(wm ? slA1 : slA0, mf * 16 + la15, ks);
#pragma unroll
    for (int nf = 0; nf < 2; ++nf)
#pragma unroll
      for (int ks = 0; ks < 2; ++ks)
        bf[0][nf][ks] = RD(slB, browb + nf * 16 + la15, ks);
    if (P0 + 6 < NP) STAGE(P0 + 6);
    __builtin_amdgcn_s_barrier();
    asm volatile("s_waitcnt lgkmcnt(0)" ::: "memory");
    __builtin_amdgcn_sched_barrier(0);
    __builtin_amdgcn_s_setprio(1);
#pragma unroll
    for (int mf = 0; mf < 4; ++mf)
#pragma unroll
      for (int nf = 0; nf < 2; ++nf)
#pragma unroll
        for (int ks = 0; ks < 2; ++ks)
          acc[mf][nf] =
              __builtin_amdgcn_mfma_f32_16x16x32_bf16(af[mf][ks], bf[0][nf][ks], acc[mf][nf], 0, 0, 0);
    __builtin_amdgcn_s_setprio(0);
    __builtin_amdgcn_s_barrier();

    // ===== phase 1: quadrant (mh0, nh1) =====
#pragma unroll
    for (int nf = 0; nf < 2; ++nf)
#pragma unroll
      for (int ks = 0; ks < 2; ++ks)
        bf[1][nf][ks] = RD(slB, browb + 32 + nf * 16 + la15, ks);
    if (P0 + 7 < NP) STAGE(P0 + 7);
    __builtin_amdgcn_s_barrier();
    asm volatile("s_waitcnt lgkmcnt(0)" ::: "memory");
    __builtin_amdgcn_sched_barrier(0);
    __builtin_amdgcn_s_setprio(1);
#pragma unroll
    for (int mf = 0; mf < 4; ++mf)
#pragma unroll
      for (int nf = 0; nf < 2; ++nf)
#pragma unroll
        for (int ks = 0; ks < 2; ++ks)
          acc[mf][2 + nf] =
              __builtin_amdgcn_mfma_f32_16x16x32_bf16(af[mf][ks], bf[1][nf][ks], acc[mf][2 + nf], 0, 0, 0);
    __builtin_amdgcn_s_setprio(0);
    __builtin_amdgcn_s_barrier();

    // ===== phase 2: quadrant (mh1, nh0) =====
#pragma unroll
    for (int mf = 0; mf < 4; ++mf)
#pragma unroll
      for (int ks = 0; ks < 2; ++ks)
        af[mf][ks] = RD(wm ? slA1 : slA0, 64 + mf * 16 + la15, ks);
    if (P0 + 8 < NP) STAGE(P0 + 8);
    __builtin_amdgcn_s_barrier();
    asm volatile("s_waitcnt lgkmcnt(0)" ::: "memory");
    __builtin_amdgcn_sched_barrier(0);
    __builtin_amdgcn_s_setprio(1);
#pragma unroll
    for (int mf = 0; mf < 4; ++mf)
#pragma unroll
      for (int nf = 0; nf < 2; ++nf)
#pragma unroll
        for (int ks = 0; ks < 2; ++ks)
          acc[4 + mf][nf] =
              __builtin_amdgcn_mfma_f32_16x16x32_bf16(af[mf][ks], bf[0][nf][ks], acc[4 + mf][nf], 0, 0, 0);
    __builtin_amdgcn_s_setprio(0);
    __builtin_amdgcn_s_barrier();

    // ===== phase 3: quadrant (mh1, nh1) =====
    if (P0 + 9 < NP) STAGE(P0 + 9);
    asm volatile("s_waitcnt vmcnt(4)" ::: "memory");  // next K-tile fully landed
    __builtin_amdgcn_s_barrier();
    __builtin_amdgcn_s_setprio(1);
#pragma unroll
    for (int mf = 0; mf < 4; ++mf)
#pragma unroll
      for (int nf = 0; nf < 2; ++nf)
#pragma unroll
        for (int ks = 0; ks < 2; ++ks)
          acc[4 + mf][2 + nf] =
              __builtin_amdgcn_mfma_f32_16x16x32_bf16(af[mf][ks], bf[1][nf][ks], acc[4 + mf][2 + nf], 0, 0, 0);
    __builtin_amdgcn_s_setprio(0);
    __builtin_amdgcn_s_barrier();
  }

  const int lr = lane >> 4, lc = lane & 15;
#pragma unroll
  for (int mq = 0; mq < 8; ++mq)
#pragma unroll
    for (int nq = 0; nq < 4; ++nq) {
      const long gcol = col0 + wn * 64 + (nq >> 1) * 32 + (nq & 1) * 16 + lc;
      const float bvv = (EPI == 5) ? 0.f : bias[gcol];
#pragma unroll
      for (int r = 0; r < 4; ++r) {
        const long grow = row0 + wm * 128 + (mq >> 2) * 64 + (mq & 3) * 16 + lr * 4 + r;
        epi_store<EPI>(out, res, grow, gcol, N, acc[mq][nq][r] + bvv);
      }
    }
}

// ---------------------------------------------------------------------------
// Offset MLP + attention softmax, one THREAD per (b,s,nh) head-row. q bf16.
// ---------------------------------------------------------------------------
__global__ __launch_bounds__(256) void offset_attn_mlp(
    const unsigned short* __restrict__ qf,
    const float* __restrict__ Wo1, const float* __restrict__ bo1,
    const float* __restrict__ Wo2, const float* __restrict__ bo2,
    const float* __restrict__ Wa, const float* __restrict__ ba,
    float* __restrict__ coords) {
  const int r = blockIdx.x * 256 + threadIdx.x;  // ((b*1024+s)*16+nh)
  const int s = (r >> 4) & 1023;

  float qr[64];
  const unsigned short* qp = qf + (long)r * 64;
#pragma unroll
  for (int i = 0; i < 8; ++i) {
    short8 v = *(const short8*)(qp + 8 * i);
#pragma unroll
    for (int j = 0; j < 8; ++j) qr[8 * i + j] = bf2f((unsigned short)v[j]);
  }

  float off[8];
#pragma unroll
  for (int o = 0; o < 8; ++o) off[o] = bo2[o];

#pragma unroll 1
  for (int jj = 0; jj < 8; ++jj) {
    float hacc[8];
#pragma unroll
    for (int o = 0; o < 8; ++o) hacc[o] = bo1[jj * 8 + o];
#pragma unroll
    for (int i = 0; i < 64; ++i) {
      const float qv = qr[i];
#pragma unroll
      for (int o = 0; o < 8; ++o) hacc[o] = fmaf(qv, Wo1[i * 64 + jj * 8 + o], hacc[o]);
    }
#pragma unroll
    for (int jo = 0; jo < 8; ++jo) {
      const float hj = fmaxf(hacc[jo], 0.f);
      const int j = jj * 8 + jo;
#pragma unroll
      for (int o = 0; o < 8; ++o) off[o] = fmaf(hj, Wo2[j * 8 + o], off[o]);
    }
  }

  float lg[4];
#pragma unroll
  for (int k = 0; k < 4; ++k) lg[k] = ba[k];
#pragma unroll
  for (int i = 0; i < 64; ++i) {
    const float qv = qr[i];
#pragma unroll
    for (int k = 0; k < 4; ++k) lg[k] = fmaf(qv, Wa[i * 4 + k], lg[k]);
  }
  const float mx = fmaxf(fmaxf(lg[0], lg[1]), fmaxf(lg[2], lg[3]));
  const float e0 = expf(lg[0] - mx), e1 = expf(lg[1] - mx), e2 = expf(lg[2] - mx),
              e3 = expf(lg[3] - mx);
  const float inv = 1.f / (e0 + e1 + e2 + e3);

  const float sx = (float)(s & 31), sy = (float)(s >> 5);
  float4 xv, yv, av;
  xv.x = sx + tanhf(off[0]) * 7.75f; yv.x = sy + tanhf(off[1]) * 7.75f;
  xv.y = sx + tanhf(off[2]) * 7.75f; yv.y = sy + tanhf(off[3]) * 7.75f;
  xv.z = sx + tanhf(off[4]) * 7.75f; yv.z = sy + tanhf(off[5]) * 7.75f;
  xv.w = sx + tanhf(off[6]) * 7.75f; yv.w = sy + tanhf(off[7]) * 7.75f;
  av.x = e0 * inv; av.y = e1 * inv; av.z = e2 * inv; av.w = e3 * inv;
  float* cp = coords + (long)r * 16;
  *(float4*)(cp + 0) = xv;
  *(float4*)(cp + 4) = yv;
  *(float4*)(cp + 8) = av;
}

// ---------------------------------------------------------------------------
// Bilinear gather + head combine, one WAVE per (b,nh,s). lane = hd.
// ---------------------------------------------------------------------------
__global__ __launch_bounds__(256) void deform_gather(
    const unsigned short* __restrict__ v_flat, const float* __restrict__ coords,
    unsigned short* __restrict__ head_out) {
  const int tid = threadIdx.x, wave = tid >> 6, lane = tid & 63;
  const int m = blockIdx.x * 4 + wave;
  const int b = m >> 14, nh = (m >> 10) & 15, s = m & 1023;
  const long r = (long)(b * 1024 + s) * 16 + nh;

  float cf = 0.f;
  if (lane < 12) cf = coords[r * 16 + lane];
  const unsigned short* vb = v_flat + ((long)(b * 16 + nh) << 16);

  float o = 0.f;
#pragma unroll
  for (int k = 0; k < 4; ++k) {
    const float xp = __shfl(cf, k), yp = __shfl(cf, 4 + k), ak = __shfl(cf, 8 + k);
    const float x0f = floorf(xp), y0f = floorf(yp);
    const int x0 = (int)x0f, y0 = (int)y0f;
    const float wx1 = xp - x0f, wy1 = yp - y0f;
    const float wx0 = 1.f - wx1, wy0 = 1.f - wy1;
    float smp = 0.f;
#pragma unroll
    for (int cn = 0; cn < 4; ++cn) {
      const int xi = x0 + (cn & 1), yi = y0 + (cn >> 1);
      const float w = (cn & 1 ? wx1 : wx0) * (cn >> 1 ? wy1 : wy0);
      const bool msk = (xi >= 0) & (xi <= 31) & (yi >= 0) & (yi <= 31);
      const int xc = min(max(xi, 0), 31), yc = min(max(yi, 0), 31);
      const float vv = bf2f(vb[(yc * 32 + xc) * 64 + lane]);
      smp = fmaf(vv, msk ? w : 0.f, smp);
    }
    o = fmaf(ak, smp, o);
  }
  head_out[r * 64 + lane] = f2bf(o);
}

// ---------------------------------------------------------------------------
extern "C" void kernel_launch(void* const* d_in, const int* in_sizes, int n_in,
                              void* d_out, int out_size, void* d_ws, size_t ws_size,
                              hipStream_t stream) {
  const float* source = (const float*)d_in[0];
  const float* target = (const float*)d_in[1];
  const float* Wq = (const float*)d_in[2];
  const float* bq = (const float*)d_in[3];
  const float* Wo1 = (const float*)d_in[4];
  const float* bo1 = (const float*)d_in[5];
  const float* Wo2 = (const float*)d_in[6];
  const float* bo2 = (const float*)d_in[7];
  const float* Wa = (const float*)d_in[8];
  const float* ba = (const float*)d_in[9];
  const float* Wv = (const float*)d_in[10];
  const float* bv = (const float*)d_in[11];
  const float* Wout = (const float*)d_in[12];
  const float* bout = (const float*)d_in[13];
  const float* gq = (const float*)d_in[14];
  const float* bq_ln = (const float*)d_in[15];
  const float* gkv = (const float*)d_in[16];
  const float* bkv_ln = (const float*)d_in[17];
  const float* gffn = (const float*)d_in[18];
  const float* bffn_ln = (const float*)d_in[19];
  const float* W1 = (const float*)d_in[20];
  const float* b1 = (const float*)d_in[21];
  const float* W2 = (const float*)d_in[22];
  const float* b2 = (const float*)d_in[23];

  char* ws = (char*)d_ws;
  const size_t MB = 1u << 20;
  if (ws_size < 150 * MB) return;  // diagnostic: leaves d_out poisoned
  const bool big = (ws_size >= 182 * MB);

  // common pre-FFN layout
  unsigned short* q_norm = (unsigned short*)(ws + 0);
  unsigned short* v_flat = (unsigned short*)(ws + 0);
  unsigned short* v_norm = (unsigned short*)(ws + 32 * MB);
  float* coords = (float*)(ws + 32 * MB);
  unsigned short* qf = (unsigned short*)(ws + 64 * MB);   // bf16 (32 MB)
  unsigned short* head_out = (unsigned short*)(ws + 96 * MB);
  // FFN-phase layout depends on path
  unsigned short* ffn_in = (unsigned short*)(big ? ws + 128 * MB : ws + 32 * MB);
  unsigned short* f_buf = (unsigned short*)(big ? ws + 0 : ws + 64 * MB);
  char* wbase = big ? ws + 160 * MB : ws + 128 * MB;
  unsigned short* Wq_t = (unsigned short*)(wbase + 0);
  unsigned short* Wv_t = (unsigned short*)(wbase + 2 * MB);
  unsigned short* Wout_t = (unsigned short*)(wbase + 4 * MB);
  unsigned short* W1_t = (unsigned short*)(wbase + 6 * MB);
  unsigned short* W2_t = (unsigned short*)(wbase + 14 * MB);
  float* src = (float*)d_out;

  dim3 tb(32, 8);
  wt_transpose_bf16<<<dim3(32, 32), tb, 0, stream>>>(Wq, Wq_t, 1024, 1024);
  wt_transpose_bf16<<<dim3(32, 32), tb, 0, stream>>>(Wv, Wv_t, 1024, 1024);
  wt_transpose_bf16<<<dim3(32, 32), tb, 0, stream>>>(Wout, Wout_t, 1024, 1024);
  wt_transpose_bf16<<<dim3(32, 128), tb, 0, stream>>>(W1, W1_t, 1024, 4096);
  wt_transpose_bf16<<<dim3(128, 32), tb, 0, stream>>>(W2, W2_t, 4096, 1024);

  ln_to_bf16<<<16384, 256, 0, stream>>>(source, gq, bq_ln, q_norm);
  ln_to_bf16<<<16384, 256, 0, stream>>>(target, gkv, bkv_ln, v_norm);

  gemm32<0><<<1024, 256, 0, stream>>>(q_norm, Wq_t, bq, nullptr, qf, 1024, 1024, 1024, 128);
  gemm32<1><<<1024, 256, 0, stream>>>(v_norm, Wv_t, bv, nullptr, v_flat, 1024, 1024, 1024, 128);

  offset_attn_mlp<<<1024, 256, 0, stream>>>(qf, Wo1, bo1, Wo2, bo2, Wa, ba, coords);
  deform_gather<<<65536, 256, 0, stream>>>(v_flat, coords, head_out);

  gemm32<2><<<1024, 256, 0, stream>>>(head_out, Wout_t, bout, source, src, 1024, 1024, 1024, 128);

  ln_to_bf16<<<16384, 256, 0, stream>>>(src, gffn, bffn_ln, ffn_in);

  if (big) {
    // merged FFN: W1 on the 8-phase TEST kernel (256^2 tiles, n_mt=64)
    gemm8p<3><<<1024, 512, 0, stream>>>(ffn_in, W1_t, b1, nullptr, f_buf, 4096, 1024, 1024, 64);
    gemm32<2><<<1024, 256, 0, stream>>>(f_buf, W2_t, b2, src, src, 1024, 4096, 4096, 128);
  } else {
    // split FFN (validated 150MB layout) — all on proven gemm32
    gemm32<3><<<2048, 256, 0, stream>>>(ffn_in, W1_t, b1, nullptr, f_buf, 2048, 1024, 1024, 128);
    gemm32<2><<<1024, 256, 0, stream>>>(f_buf, W2_t, b2, src, src, 1024, 2048, 4096, 128);
    gemm32<3><<<2048, 256, 0, stream>>>(ffn_in, W1_t + (long)2048 * 1024, b1 + 2048,
                                        nullptr, f_buf, 2048, 1024, 1024, 128);
    gemm32<5><<<1024, 256, 0, stream>>>(f_buf, W2_t + 2048, nullptr, src, src, 1024, 2048, 4096, 128);
  }
}

// Round 16
// 762.527 us; speedup vs baseline: 1.0784x; 1.0784x over previous
//
#include <hip/hip_runtime.h>

typedef __attribute__((ext_vector_type(8))) short short8;
typedef __attribute__((ext_vector_type(16))) float f32x16;

#define DEV __device__ __forceinline__

DEV float bf2f(unsigned short u) { return __uint_as_float(((unsigned)u) << 16); }
DEV unsigned short f2bf(float f) {
  unsigned u = __float_as_uint(f);
  u += 0x7FFF + ((u >> 16) & 1);   // RNE
  return (unsigned short)(u >> 16);
}

#define GLOAD_LDS16(gptr, lptr)                                                              \
  __builtin_amdgcn_global_load_lds((const __attribute__((address_space(1))) void*)(gptr),   \
                                   (__attribute__((address_space(3))) void*)(lptr), 16, 0, 0)

// ---------------------------------------------------------------------------
// Weight prep: W (K x N, fp32) -> Wt (N x K, bf16)
// ---------------------------------------------------------------------------
__global__ __launch_bounds__(256) void wt_transpose_bf16(const float* __restrict__ W,
                                                         unsigned short* __restrict__ Wt,
                                                         int K, int N) {
  __shared__ float t[32][33];
  int k0 = blockIdx.x * 32, n0 = blockIdx.y * 32;
  int tx = threadIdx.x, ty = threadIdx.y;  // 32 x 8
#pragma unroll
  for (int i = 0; i < 4; ++i)
    t[ty + 8 * i][tx] = W[(long)(k0 + ty + 8 * i) * N + n0 + tx];
  __syncthreads();
#pragma unroll
  for (int i = 0; i < 4; ++i)
    Wt[(long)(n0 + ty + 8 * i) * K + k0 + tx] = f2bf(t[tx][ty + 8 * i]);
}

// ---------------------------------------------------------------------------
// Row LayerNorm (D=1024 fixed): fp32 in -> bf16 out
// ---------------------------------------------------------------------------
__global__ __launch_bounds__(256) void ln_to_bf16(const float* __restrict__ x,
                                                  const float* __restrict__ g,
                                                  const float* __restrict__ b,
                                                  unsigned short* __restrict__ y) {
  const long row = blockIdx.x;
  const int tid = threadIdx.x;
  float4 v = *(const float4*)(x + row * 1024 + tid * 4);
  float s = v.x + v.y + v.z + v.w;
  float s2 = v.x * v.x + v.y * v.y + v.z * v.z + v.w * v.w;
#pragma unroll
  for (int o = 32; o > 0; o >>= 1) { s += __shfl_down(s, o); s2 += __shfl_down(s2, o); }
  __shared__ float red[8];
  __shared__ float mv[2];
  int wv = tid >> 6, ln = tid & 63;
  if (ln == 0) { red[wv] = s; red[4 + wv] = s2; }
  __syncthreads();
  if (tid == 0) {
    float a = red[0] + red[1] + red[2] + red[3];
    float q = red[4] + red[5] + red[6] + red[7];
    float mean = a * (1.f / 1024.f);
    mv[0] = mean;
    mv[1] = rsqrtf(q * (1.f / 1024.f) - mean * mean + 1e-5f);
  }
  __syncthreads();
  float mean = mv[0], rstd = mv[1];
  float4 gg = *(const float4*)(g + tid * 4);
  float4 bb = *(const float4*)(b + tid * 4);
  ushort4 o;
  o.x = f2bf((v.x - mean) * rstd * gg.x + bb.x);
  o.y = f2bf((v.y - mean) * rstd * gg.y + bb.y);
  o.z = f2bf((v.z - mean) * rstd * gg.z + bb.z);
  o.w = f2bf((v.w - mean) * rstd * gg.w + bb.w);
  *(ushort4*)(y + row * 1024 + tid * 4) = o;
}

// epilogue helper
// EPI: 0 +bias -> bf16 row-major (qf) | 1 +bias -> bf16 v_flat permute
//      2 +bias+res -> fp32 | 3 +bias GELU -> bf16 | 5 +res -> fp32
template <int EPI>
DEV void epi_store(void* out, const float* res, long grow, long gcol, int N, float val) {
  if (EPI == 0) {
    ((unsigned short*)out)[grow * N + gcol] = f2bf(val);
  } else if (EPI == 1) {
    const int b_ = (int)(grow >> 10), hw = (int)(grow & 1023);
    const int nh = (int)(gcol >> 6), hd = (int)(gcol & 63);
    ((unsigned short*)out)[((long)(b_ * 16 + nh) << 16) + hw * 64 + hd] = f2bf(val);
  } else if (EPI == 2) {
    ((float*)out)[grow * N + gcol] = val + res[grow * N + gcol];
  } else if (EPI == 3) {
    float gl = 0.5f * val * (1.f + erff(val * 0.70710678118654752f));
    ((unsigned short*)out)[grow * N + gcol] = f2bf(gl);
  } else {  // EPI == 5
    ((float*)out)[grow * N + gcol] = val + res[grow * N + gcol];
  }
}

// ---------------------------------------------------------------------------
// gemm32<EPI, BK>: 128x128 tile, 256 thr = 4 waves (2x2), per-wave 64x64 via
// mfma_f32_32x32x16 (acc 64 AGPR, ~124 regs -> 4 waves/SIMD). Supertiled 1D
// grid (8M x 4N per 32 blocks) for XCD L2 reuse. Single LDS buffer,
// vmcnt(0)+barrier per K-iter.
//   BK=64 : 32KB LDS, 4 blocks/CU, row=128B=8 chunks, row-pair swizzle
//           pc = kc ^ ((row>>1)&7)             [R11/R13: 0 conflicts]
//   BK=128: 64KB LDS, 2 blocks/CU, row=256B=16 chunks, swizzle
//           pc = kc ^ (row&15)                 [R9/R10 control: 0 conflicts]
//           -> halves the per-K-tile drain+barrier count (test arm: W1/W2).
// ---------------------------------------------------------------------------
template <int EPI, int BK>
__global__ __launch_bounds__(256, 4) void gemm32(const unsigned short* __restrict__ A,
                                                 const unsigned short* __restrict__ Bt,
                                                 const float* __restrict__ bias,
                                                 const float* __restrict__ res,
                                                 void* __restrict__ out,
                                                 int N, int K, int ldb, int n_mt) {
  constexpr int RB = 2 * BK;        // row bytes
  constexpr int CPR = BK / 8;       // 16B chunks per row (8 or 16)
  constexpr int CPW = BK / 16;      // 1KB staging chunks per wave (4 or 8)
  __shared__ __align__(16) char smem[BK * 512];  // A half + B half
  const int tid = threadIdx.x;
  const int wave = tid >> 6, lane = tid & 63;
  const int wm = wave >> 1, wn = wave & 1;

  const int st = blockIdx.x >> 5, wi = blockIdx.x & 31;
  const int nsm = n_mt >> 3;
  const int stm = st % nsm, stn = st / nsm;
  const long row0 = (long)(stm * 8 + (wi & 7)) * 128;
  const long col0 = (long)(stn * 4 + (wi >> 3)) * 128;

  f32x16 acc[2][2];
#pragma unroll
  for (int i = 0; i < 2; ++i)
#pragma unroll
    for (int n = 0; n < 2; ++n)
#pragma unroll
      for (int r = 0; r < 16; ++r) acc[i][n][r] = 0.f;

  // staging: 1KB chunk = (64/CPR) rows x RB bytes
  const int rin = lane / CPR, ch = lane % CPR;

  auto swz = [&](int row, int kc) -> int {
    return (BK == 64) ? (kc ^ ((row >> 1) & 7)) : (kc ^ (row & 15));
  };

  for (int kt = 0; kt < K; kt += BK) {
#pragma unroll
    for (int i = 0; i < CPW; ++i) {
      const int c = wave * CPW + i;            // chunks 0..(BK/4-1) cover 128 rows
      const int r = c * (64 / CPR) + rin;
      const int kg = swz(r, ch);               // inverse swizzle on source
      GLOAD_LDS16(A + (row0 + r) * (long)K + kt + kg * 8, smem + c * 1024);
      GLOAD_LDS16(Bt + (col0 + r) * (long)ldb + kt + kg * 8, smem + BK * 256 + c * 1024);
    }
    asm volatile("s_waitcnt vmcnt(0)" ::: "memory");
    __syncthreads();
#pragma unroll
    for (int ks = 0; ks < BK / 16; ++ks) {  // k-steps of 16
      short8 af[2], bfr[2];
      const int kc = ks * 2 + (lane >> 5);
#pragma unroll
      for (int mi = 0; mi < 2; ++mi) {
        const int rowa = wm * 64 + mi * 32 + (lane & 31);
        af[mi] = *(const short8*)(smem + rowa * RB + swz(rowa, kc) * 16);
      }
#pragma unroll
      for (int ni = 0; ni < 2; ++ni) {
        const int rowb = wn * 64 + ni * 32 + (lane & 31);
        bfr[ni] = *(const short8*)(smem + BK * 256 + rowb * RB + swz(rowb, kc) * 16);
      }
#pragma unroll
      for (int mi = 0; mi < 2; ++mi)
#pragma unroll
        for (int ni = 0; ni < 2; ++ni)
          acc[mi][ni] =
              __builtin_amdgcn_mfma_f32_32x32x16_bf16(af[mi], bfr[ni], acc[mi][ni], 0, 0, 0);
    }
    __syncthreads();
  }

  const int lc = lane & 31, lh = lane >> 5;
#pragma unroll
  for (int mi = 0; mi < 2; ++mi)
#pragma unroll
    for (int ni = 0; ni < 2; ++ni) {
      const long gcol = col0 + wn * 64 + ni * 32 + lc;
      const float bvv = (EPI == 5) ? 0.f : bias[gcol];
#pragma unroll
      for (int reg = 0; reg < 16; ++reg) {
        const long grow = row0 + wm * 64 + mi * 32 + (reg & 3) + 8 * (reg >> 2) + 4 * lh;
        epi_store<EPI>(out, res, grow, gcol, N, acc[mi][ni][reg] + bvv);
      }
    }
}

// ---------------------------------------------------------------------------
// Offset MLP + attention softmax, one THREAD per (b,s,nh) head-row. q bf16.
// ---------------------------------------------------------------------------
__global__ __launch_bounds__(256) void offset_attn_mlp(
    const unsigned short* __restrict__ qf,
    const float* __restrict__ Wo1, const float* __restrict__ bo1,
    const float* __restrict__ Wo2, const float* __restrict__ bo2,
    const float* __restrict__ Wa, const float* __restrict__ ba,
    float* __restrict__ coords) {
  const int r = blockIdx.x * 256 + threadIdx.x;  // ((b*1024+s)*16+nh)
  const int s = (r >> 4) & 1023;

  float qr[64];
  const unsigned short* qp = qf + (long)r * 64;
#pragma unroll
  for (int i = 0; i < 8; ++i) {
    short8 v = *(const short8*)(qp + 8 * i);
#pragma unroll
    for (int j = 0; j < 8; ++j) qr[8 * i + j] = bf2f((unsigned short)v[j]);
  }

  float off[8];
#pragma unroll
  for (int o = 0; o < 8; ++o) off[o] = bo2[o];

#pragma unroll 1
  for (int jj = 0; jj < 8; ++jj) {
    float hacc[8];
#pragma unroll
    for (int o = 0; o < 8; ++o) hacc[o] = bo1[jj * 8 + o];
#pragma unroll
    for (int i = 0; i < 64; ++i) {
      const float qv = qr[i];
#pragma unroll
      for (int o = 0; o < 8; ++o) hacc[o] = fmaf(qv, Wo1[i * 64 + jj * 8 + o], hacc[o]);
    }
#pragma unroll
    for (int jo = 0; jo < 8; ++jo) {
      const float hj = fmaxf(hacc[jo], 0.f);
      const int j = jj * 8 + jo;
#pragma unroll
      for (int o = 0; o < 8; ++o) off[o] = fmaf(hj, Wo2[j * 8 + o], off[o]);
    }
  }

  float lg[4];
#pragma unroll
  for (int k = 0; k < 4; ++k) lg[k] = ba[k];
#pragma unroll
  for (int i = 0; i < 64; ++i) {
    const float qv = qr[i];
#pragma unroll
    for (int k = 0; k < 4; ++k) lg[k] = fmaf(qv, Wa[i * 4 + k], lg[k]);
  }
  const float mx = fmaxf(fmaxf(lg[0], lg[1]), fmaxf(lg[2], lg[3]));
  const float e0 = expf(lg[0] - mx), e1 = expf(lg[1] - mx), e2 = expf(lg[2] - mx),
              e3 = expf(lg[3] - mx);
  const float inv = 1.f / (e0 + e1 + e2 + e3);

  const float sx = (float)(s & 31), sy = (float)(s >> 5);
  float4 xv, yv, av;
  xv.x = sx + tanhf(off[0]) * 7.75f; yv.x = sy + tanhf(off[1]) * 7.75f;
  xv.y = sx + tanhf(off[2]) * 7.75f; yv.y = sy + tanhf(off[3]) * 7.75f;
  xv.z = sx + tanhf(off[4]) * 7.75f; yv.z = sy + tanhf(off[5]) * 7.75f;
  xv.w = sx + tanhf(off[6]) * 7.75f; yv.w = sy + tanhf(off[7]) * 7.75f;
  av.x = e0 * inv; av.y = e1 * inv; av.z = e2 * inv; av.w = e3 * inv;
  float* cp = coords + (long)r * 16;
  *(float4*)(cp + 0) = xv;
  *(float4*)(cp + 4) = yv;
  *(float4*)(cp + 8) = av;
}

// ---------------------------------------------------------------------------
// Bilinear gather + head combine, one WAVE per (b,nh,s). lane = hd.
// ---------------------------------------------------------------------------
__global__ __launch_bounds__(256) void deform_gather(
    const unsigned short* __restrict__ v_flat, const float* __restrict__ coords,
    unsigned short* __restrict__ head_out) {
  const int tid = threadIdx.x, wave = tid >> 6, lane = tid & 63;
  const int m = blockIdx.x * 4 + wave;
  const int b = m >> 14, nh = (m >> 10) & 15, s = m & 1023;
  const long r = (long)(b * 1024 + s) * 16 + nh;

  float cf = 0.f;
  if (lane < 12) cf = coords[r * 16 + lane];
  const unsigned short* vb = v_flat + ((long)(b * 16 + nh) << 16);

  float o = 0.f;
#pragma unroll
  for (int k = 0; k < 4; ++k) {
    const float xp = __shfl(cf, k), yp = __shfl(cf, 4 + k), ak = __shfl(cf, 8 + k);
    const float x0f = floorf(xp), y0f = floorf(yp);
    const int x0 = (int)x0f, y0 = (int)y0f;
    const float wx1 = xp - x0f, wy1 = yp - y0f;
    const float wx0 = 1.f - wx1, wy0 = 1.f - wy1;
    float smp = 0.f;
#pragma unroll
    for (int cn = 0; cn < 4; ++cn) {
      const int xi = x0 + (cn & 1), yi = y0 + (cn >> 1);
      const float w = (cn & 1 ? wx1 : wx0) * (cn >> 1 ? wy1 : wy0);
      const bool msk = (xi >= 0) & (xi <= 31) & (yi >= 0) & (yi <= 31);
      const int xc = min(max(xi, 0), 31), yc = min(max(yi, 0), 31);
      const float vv = bf2f(vb[(yc * 32 + xc) * 64 + lane]);
      smp = fmaf(vv, msk ? w : 0.f, smp);
    }
    o = fmaf(ak, smp, o);
  }
  head_out[r * 64 + lane] = f2bf(o);
}

// ---------------------------------------------------------------------------
extern "C" void kernel_launch(void* const* d_in, const int* in_sizes, int n_in,
                              void* d_out, int out_size, void* d_ws, size_t ws_size,
                              hipStream_t stream) {
  const float* source = (const float*)d_in[0];
  const float* target = (const float*)d_in[1];
  const float* Wq = (const float*)d_in[2];
  const float* bq = (const float*)d_in[3];
  const float* Wo1 = (const float*)d_in[4];
  const float* bo1 = (const float*)d_in[5];
  const float* Wo2 = (const float*)d_in[6];
  const float* bo2 = (const float*)d_in[7];
  const float* Wa = (const float*)d_in[8];
  const float* ba = (const float*)d_in[9];
  const float* Wv = (const float*)d_in[10];
  const float* bv = (const float*)d_in[11];
  const float* Wout = (const float*)d_in[12];
  const float* bout = (const float*)d_in[13];
  const float* gq = (const float*)d_in[14];
  const float* bq_ln = (const float*)d_in[15];
  const float* gkv = (const float*)d_in[16];
  const float* bkv_ln = (const float*)d_in[17];
  const float* gffn = (const float*)d_in[18];
  const float* bffn_ln = (const float*)d_in[19];
  const float* W1 = (const float*)d_in[20];
  const float* b1 = (const float*)d_in[21];
  const float* W2 = (const float*)d_in[22];
  const float* b2 = (const float*)d_in[23];

  char* ws = (char*)d_ws;
  const size_t MB = 1u << 20;
  if (ws_size < 150 * MB) return;  // diagnostic: leaves d_out poisoned
  const bool big = (ws_size >= 182 * MB);

  // common pre-FFN layout
  unsigned short* q_norm = (unsigned short*)(ws + 0);
  unsigned short* v_flat = (unsigned short*)(ws + 0);
  unsigned short* v_norm = (unsigned short*)(ws + 32 * MB);
  float* coords = (float*)(ws + 32 * MB);
  unsigned short* qf = (unsigned short*)(ws + 64 * MB);   // bf16 (32 MB)
  unsigned short* head_out = (unsigned short*)(ws + 96 * MB);
  // FFN-phase layout depends on path
  unsigned short* ffn_in = (unsigned short*)(big ? ws + 128 * MB : ws + 32 * MB);
  unsigned short* f_buf = (unsigned short*)(big ? ws + 0 : ws + 64 * MB);
  char* wbase = big ? ws + 160 * MB : ws + 128 * MB;
  unsigned short* Wq_t = (unsigned short*)(wbase + 0);
  unsigned short* Wv_t = (unsigned short*)(wbase + 2 * MB);
  unsigned short* Wout_t = (unsigned short*)(wbase + 4 * MB);
  unsigned short* W1_t = (unsigned short*)(wbase + 6 * MB);
  unsigned short* W2_t = (unsigned short*)(wbase + 14 * MB);
  float* src = (float*)d_out;

  dim3 tb(32, 8);
  wt_transpose_bf16<<<dim3(32, 32), tb, 0, stream>>>(Wq, Wq_t, 1024, 1024);
  wt_transpose_bf16<<<dim3(32, 32), tb, 0, stream>>>(Wv, Wv_t, 1024, 1024);
  wt_transpose_bf16<<<dim3(32, 32), tb, 0, stream>>>(Wout, Wout_t, 1024, 1024);
  wt_transpose_bf16<<<dim3(32, 128), tb, 0, stream>>>(W1, W1_t, 1024, 4096);
  wt_transpose_bf16<<<dim3(128, 32), tb, 0, stream>>>(W2, W2_t, 4096, 1024);

  ln_to_bf16<<<16384, 256, 0, stream>>>(source, gq, bq_ln, q_norm);
  ln_to_bf16<<<16384, 256, 0, stream>>>(target, gkv, bkv_ln, v_norm);

  // control arm: BK=64 (proven R13/R14)
  gemm32<0, 64><<<1024, 256, 0, stream>>>(q_norm, Wq_t, bq, nullptr, qf, 1024, 1024, 1024, 128);
  gemm32<1, 64><<<1024, 256, 0, stream>>>(v_norm, Wv_t, bv, nullptr, v_flat, 1024, 1024, 1024, 128);

  offset_attn_mlp<<<1024, 256, 0, stream>>>(qf, Wo1, bo1, Wo2, bo2, Wa, ba, coords);
  deform_gather<<<65536, 256, 0, stream>>>(v_flat, coords, head_out);

  gemm32<2, 64><<<1024, 256, 0, stream>>>(head_out, Wout_t, bout, source, src, 1024, 1024, 1024, 128);

  ln_to_bf16<<<16384, 256, 0, stream>>>(src, gffn, bffn_ln, ffn_in);

  if (big) {
    // merged FFN — test arm: BK=128 (half the drain/barrier count)
    gemm32<3, 128><<<4096, 256, 0, stream>>>(ffn_in, W1_t, b1, nullptr, f_buf, 4096, 1024, 1024, 128);
    gemm32<2, 128><<<1024, 256, 0, stream>>>(f_buf, W2_t, b2, src, src, 1024, 4096, 4096, 128);
  } else {
    // split FFN (validated 150MB layout) — test arm on halves too
    gemm32<3, 128><<<2048, 256, 0, stream>>>(ffn_in, W1_t, b1, nullptr, f_buf, 2048, 1024, 1024, 128);
    gemm32<2, 128><<<1024, 256, 0, stream>>>(f_buf, W2_t, b2, src, src, 1024, 2048, 4096, 128);
    gemm32<3, 128><<<2048, 256, 0, stream>>>(ffn_in, W1_t + (long)2048 * 1024, b1 + 2048,
                                             nullptr, f_buf, 2048, 1024, 1024, 128);
    gemm32<5, 128><<<1024, 256, 0, stream>>>(f_buf, W2_t + 2048, nullptr, src, src, 1024, 2048, 4096, 128);
  }
}

// Round 17
// 700.760 us; speedup vs baseline: 1.1734x; 1.0881x over previous
//
#include <hip/hip_runtime.h>

typedef __attribute__((ext_vector_type(8))) short short8;
typedef __attribute__((ext_vector_type(16))) float f32x16;

#define DEV __device__ __forceinline__

DEV float bf2f(unsigned short u) { return __uint_as_float(((unsigned)u) << 16); }
DEV unsigned short f2bf(float f) {
  unsigned u = __float_as_uint(f);
  u += 0x7FFF + ((u >> 16) & 1);   // RNE
  return (unsigned short)(u >> 16);
}

#define GLOAD_LDS16(gptr, lptr)                                                              \
  __builtin_amdgcn_global_load_lds((const __attribute__((address_space(1))) void*)(gptr),   \
                                   (__attribute__((address_space(3))) void*)(lptr), 16, 0, 0)

// ---------------------------------------------------------------------------
// Weight prep: W (K x N, fp32) -> Wt (N x K, bf16)
// ---------------------------------------------------------------------------
__global__ __launch_bounds__(256) void wt_transpose_bf16(const float* __restrict__ W,
                                                         unsigned short* __restrict__ Wt,
                                                         int K, int N) {
  __shared__ float t[32][33];
  int k0 = blockIdx.x * 32, n0 = blockIdx.y * 32;
  int tx = threadIdx.x, ty = threadIdx.y;  // 32 x 8
#pragma unroll
  for (int i = 0; i < 4; ++i)
    t[ty + 8 * i][tx] = W[(long)(k0 + ty + 8 * i) * N + n0 + tx];
  __syncthreads();
#pragma unroll
  for (int i = 0; i < 4; ++i)
    Wt[(long)(n0 + ty + 8 * i) * K + k0 + tx] = f2bf(t[tx][ty + 8 * i]);
}

// ---------------------------------------------------------------------------
// Row LayerNorm (D=1024): fp32 in -> bf16 out. Dual-tensor variant: grid
// [0,16384) -> x0/y0, [16384,32768) -> x1/y1 (merges the two input LNs).
// ---------------------------------------------------------------------------
__global__ __launch_bounds__(256) void ln_to_bf16_dual(
    const float* __restrict__ x0, const float* __restrict__ g0, const float* __restrict__ b0,
    unsigned short* __restrict__ y0,
    const float* __restrict__ x1, const float* __restrict__ g1, const float* __restrict__ b1,
    unsigned short* __restrict__ y1) {
  const bool second = blockIdx.x >= 16384;
  const long row = second ? blockIdx.x - 16384 : blockIdx.x;
  const float* x = second ? x1 : x0;
  const float* g = second ? g1 : g0;
  const float* b = second ? b1 : b0;
  unsigned short* y = second ? y1 : y0;
  const int tid = threadIdx.x;
  float4 v = *(const float4*)(x + row * 1024 + tid * 4);
  float s = v.x + v.y + v.z + v.w;
  float s2 = v.x * v.x + v.y * v.y + v.z * v.z + v.w * v.w;
#pragma unroll
  for (int o = 32; o > 0; o >>= 1) { s += __shfl_down(s, o); s2 += __shfl_down(s2, o); }
  __shared__ float red[8];
  __shared__ float mv[2];
  int wv = tid >> 6, ln = tid & 63;
  if (ln == 0) { red[wv] = s; red[4 + wv] = s2; }
  __syncthreads();
  if (tid == 0) {
    float a = red[0] + red[1] + red[2] + red[3];
    float q = red[4] + red[5] + red[6] + red[7];
    float mean = a * (1.f / 1024.f);
    mv[0] = mean;
    mv[1] = rsqrtf(q * (1.f / 1024.f) - mean * mean + 1e-5f);
  }
  __syncthreads();
  float mean = mv[0], rstd = mv[1];
  float4 gg = *(const float4*)(g + tid * 4);
  float4 bb = *(const float4*)(b + tid * 4);
  ushort4 o;
  o.x = f2bf((v.x - mean) * rstd * gg.x + bb.x);
  o.y = f2bf((v.y - mean) * rstd * gg.y + bb.y);
  o.z = f2bf((v.z - mean) * rstd * gg.z + bb.z);
  o.w = f2bf((v.w - mean) * rstd * gg.w + bb.w);
  *(ushort4*)(y + row * 1024 + tid * 4) = o;
}

// single-tensor LN (post-attention)
__global__ __launch_bounds__(256) void ln_to_bf16(const float* __restrict__ x,
                                                  const float* __restrict__ g,
                                                  const float* __restrict__ b,
                                                  unsigned short* __restrict__ y) {
  const long row = blockIdx.x;
  const int tid = threadIdx.x;
  float4 v = *(const float4*)(x + row * 1024 + tid * 4);
  float s = v.x + v.y + v.z + v.w;
  float s2 = v.x * v.x + v.y * v.y + v.z * v.z + v.w * v.w;
#pragma unroll
  for (int o = 32; o > 0; o >>= 1) { s += __shfl_down(s, o); s2 += __shfl_down(s2, o); }
  __shared__ float red[8];
  __shared__ float mv[2];
  int wv = tid >> 6, ln = tid & 63;
  if (ln == 0) { red[wv] = s; red[4 + wv] = s2; }
  __syncthreads();
  if (tid == 0) {
    float a = red[0] + red[1] + red[2] + red[3];
    float q = red[4] + red[5] + red[6] + red[7];
    float mean = a * (1.f / 1024.f);
    mv[0] = mean;
    mv[1] = rsqrtf(q * (1.f / 1024.f) - mean * mean + 1e-5f);
  }
  __syncthreads();
  float mean = mv[0], rstd = mv[1];
  float4 gg = *(const float4*)(g + tid * 4);
  float4 bb = *(const float4*)(b + tid * 4);
  ushort4 o;
  o.x = f2bf((v.x - mean) * rstd * gg.x + bb.x);
  o.y = f2bf((v.y - mean) * rstd * gg.y + bb.y);
  o.z = f2bf((v.z - mean) * rstd * gg.z + bb.z);
  o.w = f2bf((v.w - mean) * rstd * gg.w + bb.w);
  *(ushort4*)(y + row * 1024 + tid * 4) = o;
}

// epilogue helper
// EPI: 0 +bias -> bf16 row-major (qf) | 1 +bias -> bf16 v_flat permute
//      2 +bias+res -> fp32 | 3 +bias GELU(tanh) -> bf16 | 5 +res -> fp32
template <int EPI>
DEV void epi_store(void* out, const float* res, long grow, long gcol, int N, float val) {
  if (EPI == 0) {
    ((unsigned short*)out)[grow * N + gcol] = f2bf(val);
  } else if (EPI == 1) {
    const int b_ = (int)(grow >> 10), hw = (int)(grow & 1023);
    const int nh = (int)(gcol >> 6), hd = (int)(gcol & 63);
    ((unsigned short*)out)[((long)(b_ * 16 + nh) << 16) + hw * 64 + hd] = f2bf(val);
  } else if (EPI == 2) {
    ((float*)out)[grow * N + gcol] = val + res[grow * N + gcol];
  } else if (EPI == 3) {
    // tanh-form GELU: max |err| vs exact-erf ~3e-4, far below bf16 rounding
    const float c = 0.79788456080286536f;  // sqrt(2/pi)
    float t = tanhf(c * (val + 0.044715f * val * val * val));
    ((unsigned short*)out)[grow * N + gcol] = f2bf(0.5f * val * (1.f + t));
  } else {  // EPI == 5
    ((float*)out)[grow * N + gcol] = val + res[grow * N + gcol];
  }
}

// ---------------------------------------------------------------------------
// gemm32 (proven R13/R14 config): 128x128 tile, BK=64, 256 thr = 4 waves
// (2x2), per-wave 64x64 via mfma_f32_32x32x16 (acc 64 AGPR, ~124 regs ->
// 4 blocks/CU). Row-pair XOR swizzle pc = kc ^ ((row>>1)&7), inverse on
// staging source (0 conflicts, R11/R13). Supertiled 1D grid (8M x 4N per
// 32 blocks) for XCD L2 reuse. Single LDS buffer, vmcnt(0)+barrier/K-iter.
// Established plateau for K=1024 shapes: ~560 TF (R7-R16 design-space map).
// ---------------------------------------------------------------------------
template <int EPI>
__global__ __launch_bounds__(256, 4) void gemm32(const unsigned short* __restrict__ A,
                                                 const unsigned short* __restrict__ Bt,
                                                 const float* __restrict__ bias,
                                                 const float* __restrict__ res,
                                                 void* __restrict__ out,
                                                 int N, int K, int ldb, int n_mt) {
  __shared__ __align__(16) char smem[32768];  // A 16KB + B 16KB
  const int tid = threadIdx.x;
  const int wave = tid >> 6, lane = tid & 63;
  const int wm = wave >> 1, wn = wave & 1;

  const int st = blockIdx.x >> 5, wi = blockIdx.x & 31;
  const int nsm = n_mt >> 3;
  const int stm = st % nsm, stn = st / nsm;
  const long row0 = (long)(stm * 8 + (wi & 7)) * 128;
  const long col0 = (long)(stn * 4 + (wi >> 3)) * 128;

  f32x16 acc[2][2];
#pragma unroll
  for (int i = 0; i < 2; ++i)
#pragma unroll
    for (int n = 0; n < 2; ++n)
#pragma unroll
      for (int r = 0; r < 16; ++r) acc[i][n][r] = 0.f;

  const int rin = lane >> 3, ch = lane & 7;  // chunk = 1KB = 8 rows x 128B

  for (int kt = 0; kt < K; kt += 64) {
#pragma unroll
    for (int i = 0; i < 4; ++i) {
      const int c = wave * 4 + i;
      const int r = c * 8 + rin;
      const int kg = ch ^ ((r >> 1) & 7);
      GLOAD_LDS16(A + (row0 + r) * (long)K + kt + kg * 8, smem + c * 1024);
      GLOAD_LDS16(Bt + (col0 + r) * (long)ldb + kt + kg * 8, smem + 16384 + c * 1024);
    }
    asm volatile("s_waitcnt vmcnt(0)" ::: "memory");
    __syncthreads();
#pragma unroll
    for (int ks = 0; ks < 4; ++ks) {
      short8 af[2], bfr[2];
      const int kc = ks * 2 + (lane >> 5);
#pragma unroll
      for (int mi = 0; mi < 2; ++mi) {
        const int rowa = wm * 64 + mi * 32 + (lane & 31);
        af[mi] = *(const short8*)(smem + rowa * 128 + (kc ^ ((rowa >> 1) & 7)) * 16);
      }
#pragma unroll
      for (int ni = 0; ni < 2; ++ni) {
        const int rowb = wn * 64 + ni * 32 + (lane & 31);
        bfr[ni] = *(const short8*)(smem + 16384 + rowb * 128 + (kc ^ ((rowb >> 1) & 7)) * 16);
      }
#pragma unroll
      for (int mi = 0; mi < 2; ++mi)
#pragma unroll
        for (int ni = 0; ni < 2; ++ni)
          acc[mi][ni] =
              __builtin_amdgcn_mfma_f32_32x32x16_bf16(af[mi], bfr[ni], acc[mi][ni], 0, 0, 0);
    }
    __syncthreads();
  }

  const int lc = lane & 31, lh = lane >> 5;
#pragma unroll
  for (int mi = 0; mi < 2; ++mi)
#pragma unroll
    for (int ni = 0; ni < 2; ++ni) {
      const long gcol = col0 + wn * 64 + ni * 32 + lc;
      const float bvv = (EPI == 5) ? 0.f : bias[gcol];
#pragma unroll
      for (int reg = 0; reg < 16; ++reg) {
        const long grow = row0 + wm * 64 + mi * 32 + (reg & 3) + 8 * (reg >> 2) + 4 * lh;
        epi_store<EPI>(out, res, grow, gcol, N, acc[mi][ni][reg] + bvv);
      }
    }
}

// ---------------------------------------------------------------------------
// Offset MLP + attention softmax, one THREAD per (b,s,nh) head-row. q bf16.
// ---------------------------------------------------------------------------
__global__ __launch_bounds__(256) void offset_attn_mlp(
    const unsigned short* __restrict__ qf,
    const float* __restrict__ Wo1, const float* __restrict__ bo1,
    const float* __restrict__ Wo2, const float* __restrict__ bo2,
    const float* __restrict__ Wa, const float* __restrict__ ba,
    float* __restrict__ coords) {
  const int r = blockIdx.x * 256 + threadIdx.x;  // ((b*1024+s)*16+nh)
  const int s = (r >> 4) & 1023;

  float qr[64];
  const unsigned short* qp = qf + (long)r * 64;
#pragma unroll
  for (int i = 0; i < 8; ++i) {
    short8 v = *(const short8*)(qp + 8 * i);
#pragma unroll
    for (int j = 0; j < 8; ++j) qr[8 * i + j] = bf2f((unsigned short)v[j]);
  }

  float off[8];
#pragma unroll
  for (int o = 0; o < 8; ++o) off[o] = bo2[o];

#pragma unroll 1
  for (int jj = 0; jj < 8; ++jj) {
    float hacc[8];
#pragma unroll
    for (int o = 0; o < 8; ++o) hacc[o] = bo1[jj * 8 + o];
#pragma unroll
    for (int i = 0; i < 64; ++i) {
      const float qv = qr[i];
#pragma unroll
      for (int o = 0; o < 8; ++o) hacc[o] = fmaf(qv, Wo1[i * 64 + jj * 8 + o], hacc[o]);
    }
#pragma unroll
    for (int jo = 0; jo < 8; ++jo) {
      const float hj = fmaxf(hacc[jo], 0.f);
      const int j = jj * 8 + jo;
#pragma unroll
      for (int o = 0; o < 8; ++o) off[o] = fmaf(hj, Wo2[j * 8 + o], off[o]);
    }
  }

  float lg[4];
#pragma unroll
  for (int k = 0; k < 4; ++k) lg[k] = ba[k];
#pragma unroll
  for (int i = 0; i < 64; ++i) {
    const float qv = qr[i];
#pragma unroll
    for (int k = 0; k < 4; ++k) lg[k] = fmaf(qv, Wa[i * 4 + k], lg[k]);
  }
  const float mx = fmaxf(fmaxf(lg[0], lg[1]), fmaxf(lg[2], lg[3]));
  const float e0 = expf(lg[0] - mx), e1 = expf(lg[1] - mx), e2 = expf(lg[2] - mx),
              e3 = expf(lg[3] - mx);
  const float inv = 1.f / (e0 + e1 + e2 + e3);

  const float sx = (float)(s & 31), sy = (float)(s >> 5);
  float4 xv, yv, av;
  xv.x = sx + tanhf(off[0]) * 7.75f; yv.x = sy + tanhf(off[1]) * 7.75f;
  xv.y = sx + tanhf(off[2]) * 7.75f; yv.y = sy + tanhf(off[3]) * 7.75f;
  xv.z = sx + tanhf(off[4]) * 7.75f; yv.z = sy + tanhf(off[5]) * 7.75f;
  xv.w = sx + tanhf(off[6]) * 7.75f; yv.w = sy + tanhf(off[7]) * 7.75f;
  av.x = e0 * inv; av.y = e1 * inv; av.z = e2 * inv; av.w = e3 * inv;
  float* cp = coords + (long)r * 16;
  *(float4*)(cp + 0) = xv;
  *(float4*)(cp + 4) = yv;
  *(float4*)(cp + 8) = av;
}

// ---------------------------------------------------------------------------
// Bilinear gather + head combine, one WAVE per (b,nh,s). lane = hd.
// ---------------------------------------------------------------------------
__global__ __launch_bounds__(256) void deform_gather(
    const unsigned short* __restrict__ v_flat, const float* __restrict__ coords,
    unsigned short* __restrict__ head_out) {
  const int tid = threadIdx.x, wave = tid >> 6, lane = tid & 63;
  const int m = blockIdx.x * 4 + wave;
  const int b = m >> 14, nh = (m >> 10) & 15, s = m & 1023;
  const long r = (long)(b * 1024 + s) * 16 + nh;

  float cf = 0.f;
  if (lane < 12) cf = coords[r * 16 + lane];
  const unsigned short* vb = v_flat + ((long)(b * 16 + nh) << 16);

  float o = 0.f;
#pragma unroll
  for (int k = 0; k < 4; ++k) {
    const float xp = __shfl(cf, k), yp = __shfl(cf, 4 + k), ak = __shfl(cf, 8 + k);
    const float x0f = floorf(xp), y0f = floorf(yp);
    const int x0 = (int)x0f, y0 = (int)y0f;
    const float wx1 = xp - x0f, wy1 = yp - y0f;
    const float wx0 = 1.f - wx1, wy0 = 1.f - wy1;
    float smp = 0.f;
#pragma unroll
    for (int cn = 0; cn < 4; ++cn) {
      const int xi = x0 + (cn & 1), yi = y0 + (cn >> 1);
      const float w = (cn & 1 ? wx1 : wx0) * (cn >> 1 ? wy1 : wy0);
      const bool msk = (xi >= 0) & (xi <= 31) & (yi >= 0) & (yi <= 31);
      const int xc = min(max(xi, 0), 31), yc = min(max(yi, 0), 31);
      const float vv = bf2f(vb[(yc * 32 + xc) * 64 + lane]);
      smp = fmaf(vv, msk ? w : 0.f, smp);
    }
    o = fmaf(ak, smp, o);
  }
  head_out[r * 64 + lane] = f2bf(o);
}

// ---------------------------------------------------------------------------
extern "C" void kernel_launch(void* const* d_in, const int* in_sizes, int n_in,
                              void* d_out, int out_size, void* d_ws, size_t ws_size,
                              hipStream_t stream) {
  const float* source = (const float*)d_in[0];
  const float* target = (const float*)d_in[1];
  const float* Wq = (const float*)d_in[2];
  const float* bq = (const float*)d_in[3];
  const float* Wo1 = (const float*)d_in[4];
  const float* bo1 = (const float*)d_in[5];
  const float* Wo2 = (const float*)d_in[6];
  const float* bo2 = (const float*)d_in[7];
  const float* Wa = (const float*)d_in[8];
  const float* ba = (const float*)d_in[9];
  const float* Wv = (const float*)d_in[10];
  const float* bv = (const float*)d_in[11];
  const float* Wout = (const float*)d_in[12];
  const float* bout = (const float*)d_in[13];
  const float* gq = (const float*)d_in[14];
  const float* bq_ln = (const float*)d_in[15];
  const float* gkv = (const float*)d_in[16];
  const float* bkv_ln = (const float*)d_in[17];
  const float* gffn = (const float*)d_in[18];
  const float* bffn_ln = (const float*)d_in[19];
  const float* W1 = (const float*)d_in[20];
  const float* b1 = (const float*)d_in[21];
  const float* W2 = (const float*)d_in[22];
  const float* b2 = (const float*)d_in[23];

  char* ws = (char*)d_ws;
  const size_t MB = 1u << 20;
  if (ws_size < 150 * MB) return;  // diagnostic: leaves d_out poisoned
  const bool big = (ws_size >= 182 * MB);

  // common pre-FFN layout
  unsigned short* q_norm = (unsigned short*)(ws + 0);
  unsigned short* v_flat = (unsigned short*)(ws + 0);
  unsigned short* v_norm = (unsigned short*)(ws + 32 * MB);
  float* coords = (float*)(ws + 32 * MB);
  unsigned short* qf = (unsigned short*)(ws + 64 * MB);   // bf16 (32 MB)
  unsigned short* head_out = (unsigned short*)(ws + 96 * MB);
  // FFN-phase layout depends on path
  unsigned short* ffn_in = (unsigned short*)(big ? ws + 128 * MB : ws + 32 * MB);
  unsigned short* f_buf = (unsigned short*)(big ? ws + 0 : ws + 64 * MB);
  char* wbase = big ? ws + 160 * MB : ws + 128 * MB;
  unsigned short* Wq_t = (unsigned short*)(wbase + 0);
  unsigned short* Wv_t = (unsigned short*)(wbase + 2 * MB);
  unsigned short* Wout_t = (unsigned short*)(wbase + 4 * MB);
  unsigned short* W1_t = (unsigned short*)(wbase + 6 * MB);
  unsigned short* W2_t = (unsigned short*)(wbase + 14 * MB);
  float* src = (float*)d_out;

  dim3 tb(32, 8);
  wt_transpose_bf16<<<dim3(32, 32), tb, 0, stream>>>(Wq, Wq_t, 1024, 1024);
  wt_transpose_bf16<<<dim3(32, 32), tb, 0, stream>>>(Wv, Wv_t, 1024, 1024);
  wt_transpose_bf16<<<dim3(32, 32), tb, 0, stream>>>(Wout, Wout_t, 1024, 1024);
  wt_transpose_bf16<<<dim3(32, 128), tb, 0, stream>>>(W1, W1_t, 1024, 4096);
  wt_transpose_bf16<<<dim3(128, 32), tb, 0, stream>>>(W2, W2_t, 4096, 1024);

  // merged input LayerNorms (one dispatch)
  ln_to_bf16_dual<<<32768, 256, 0, stream>>>(source, gq, bq_ln, q_norm,
                                             target, gkv, bkv_ln, v_norm);

  gemm32<0><<<1024, 256, 0, stream>>>(q_norm, Wq_t, bq, nullptr, qf, 1024, 1024, 1024, 128);
  gemm32<1><<<1024, 256, 0, stream>>>(v_norm, Wv_t, bv, nullptr, v_flat, 1024, 1024, 1024, 128);

  offset_attn_mlp<<<1024, 256, 0, stream>>>(qf, Wo1, bo1, Wo2, bo2, Wa, ba, coords);
  deform_gather<<<65536, 256, 0, stream>>>(v_flat, coords, head_out);

  gemm32<2><<<1024, 256, 0, stream>>>(head_out, Wout_t, bout, source, src, 1024, 1024, 1024, 128);

  ln_to_bf16<<<16384, 256, 0, stream>>>(src, gffn, bffn_ln, ffn_in);

  if (big) {
    // merged FFN (BK=64, proven R14 config)
    gemm32<3><<<4096, 256, 0, stream>>>(ffn_in, W1_t, b1, nullptr, f_buf, 4096, 1024, 1024, 128);
    gemm32<2><<<1024, 256, 0, stream>>>(f_buf, W2_t, b2, src, src, 1024, 4096, 4096, 128);
  } else {
    // split FFN (validated 150MB layout)
    gemm32<3><<<2048, 256, 0, stream>>>(ffn_in, W1_t, b1, nullptr, f_buf, 2048, 1024, 1024, 128);
    gemm32<2><<<1024, 256, 0, stream>>>(f_buf, W2_t, b2, src, src, 1024, 2048, 4096, 128);
    gemm32<3><<<2048, 256, 0, stream>>>(ffn_in, W1_t + (long)2048 * 1024, b1 + 2048,
                                        nullptr, f_buf, 2048, 1024, 1024, 128);
    gemm32<5><<<1024, 256, 0, stream>>>(f_buf, W2_t + 2048, nullptr, src, src, 1024, 2048, 4096, 128);
  }
}